// Round 16
// baseline (303.875 us; speedup 1.0000x reference)
//
#include <hip/hip_runtime.h>
#include <hip/hip_bf16.h>
#include <stdint.h>

#define IN_SZ   256
#define OUT_SZ  256
#define RANK    60
#define NSEL    256
#define BATCH   1024
#define WELEMS  (IN_SZ * OUT_SZ)   // 65536 elems per channel

typedef __attribute__((ext_vector_type(8))) short          short8;
typedef __attribute__((ext_vector_type(4))) float          f32x4;

static __device__ __forceinline__ unsigned short f32_to_bf16(float f) {
    union { float f; uint32_t u; } c; c.f = f;
    uint32_t u = c.u;
    u += 0x7fffu + ((u >> 16) & 1u);   // RNE
    return (unsigned short)(u >> 16);
}

// pair-packed RNE convert — compiler emits v_cvt_pk_bf16_f32 (same rounding)
static __device__ __forceinline__ short8 cvt8(f32x4 lo, f32x4 hi) {
    union { short8 s; __hip_bfloat162 h[4]; } u;
    u.h[0] = __float22bfloat162_rn(make_float2(lo[0], lo[1]));
    u.h[1] = __float22bfloat162_rn(make_float2(lo[2], lo[3]));
    u.h[2] = __float22bfloat162_rn(make_float2(hi[0], hi[1]));
    u.h[3] = __float22bfloat162_rn(make_float2(hi[2], hi[3]));
    return u.s;
}

// -----------------------------------------------------------------------------
// Kernel 1: W_sel = U[idx] @ V -> bf16 in B-FRAGMENT-MAJOR layout:
//   wt[n][koct*2048 + o*8 + il]   (koct = i>>3, il = i&7)
// (unchanged — verified correct, ~24 µs)
// -----------------------------------------------------------------------------
__global__ __launch_bounds__(256) void synth_w(
    const float* __restrict__ U, const float* __restrict__ V,
    const int* __restrict__ idx, unsigned short* __restrict__ wt)
{
    __shared__ unsigned short Cs[16][2064];

    int bid = blockIdx.x;                  // 512 blocks
    int L   = (bid & 7) * 64 + (bid >> 3); // XCD swizzle: same-ic -> same XCD
    int ic  = L >> 4;
    int g16 = L & 15;

    int tid = threadIdx.x, lane = tid & 63, wv = tid >> 6;

    int arow = lane & 15;
    int c    = idx[g16 * 16 + arow];
    short8 afr[2];
    #pragma unroll
    for (int ks = 0; ks < 2; ++ks) {
        short8 h;
        #pragma unroll
        for (int j = 0; j < 8; ++j) {
            int r = ks * 32 + (lane >> 4) * 8 + j;
            float u = (r < RANK) ? U[c * RANK + r] : 0.f;
            h[j] = (short)f32_to_bf16(u);
        }
        afr[ks] = h;
    }

    const float* Vb = V + (size_t)ic * 2048;
    #pragma unroll 2
    for (int mt = 0; mt < 32; ++mt) {
        int mloc = (wv * 32 + mt) * 16 + (lane & 15);
        f32x4 acc = {};
        #pragma unroll
        for (int ks = 0; ks < 2; ++ks) {
            short8 b;
            #pragma unroll
            for (int j = 0; j < 8; ++j) {
                int r = ks * 32 + (lane >> 4) * 8 + j;
                float v = (r < RANK) ? Vb[(size_t)r * WELEMS + mloc] : 0.f;
                b[j] = (short)f32_to_bf16(v);
            }
            acc = __builtin_amdgcn_mfma_f32_16x16x32_bf16(afr[ks], b, acc, 0, 0, 0);
        }
        #pragma unroll
        for (int j = 0; j < 4; ++j) {
            int nl = (lane >> 4) * 4 + j;
            Cs[nl][wv * 512 + mt * 16 + (lane & 15)] = f32_to_bf16(acc[j]);
        }
    }
    __syncthreads();

    #pragma unroll
    for (int t0 = 0; t0 < 16; ++t0) {
        int t  = t0 * 256 + tid;
        int nl = t >> 8;
        int o  = t & 255;
        short8 h;
        #pragma unroll
        for (int il = 0; il < 8; ++il) h[il] = (short)Cs[nl][il * 256 + o];
        int n = g16 * 16 + nl;
        size_t base = (size_t)n * WELEMS + (size_t)ic * 2048 + (size_t)o * 8;
        *reinterpret_cast<short8*>(wt + base) = h;
    }
}

// -----------------------------------------------------------------------------
// Kernel 2: B-IN-REGISTERS GEMM. Zero LDS, zero barriers. 2048 blocks of 256
// threads; block = (n, col-half cb, row-quarter rb); wave owns 32 cols x 256
// rows. Its W column-slice (8 ks x 2 nf x short8 = 64 VGPR) is loaded from
// global ONCE (L2-hot, same-n blocks XCD-pinned); bias in 2 regs; acc init =
// bias. Steady state: only the A-stream touches memory — per-lane coalesced
// global x loads, half-tile double buffer (R15's proven scheme). No per-MFMA
// LDS reads (R15 paid 8.4 MB/CU = ~41 us of LDS pipe), no vmcnt/lgkm coupling.
// __launch_bounds__(256,3): cap ~170 regs, demand ~130 -> no spill; 3 blk/CU.
// -----------------------------------------------------------------------------
__global__ __launch_bounds__(256, 3) void gemm_k(
    const float* __restrict__ x, const int* __restrict__ idx,
    const unsigned short* __restrict__ wt, const float* __restrict__ bias,
    float* __restrict__ out)
{
    int bid = blockIdx.x;                  // 2048 blocks
    int L   = (bid & 7) * 256 + (bid >> 3);
    int n   = L >> 3;                      // 8 blocks of same n -> same XCD
    int sub = L & 7;
    int cb  = sub & 1;                     // col half   (128 cols)
    int rb  = sub >> 1;                    // row quarter (256 rows)

    int tid  = threadIdx.x;
    int lane = tid & 63;
    int wv   = tid >> 6;                   // 0..3
    int r16  = lane & 15;
    int q    = lane >> 4;

    int col0 = cb * 128 + wv * 32;         // wave's 32-col base

    // ---- B into registers: 16 x dwordx4, once ----
    const unsigned short* wq = wt + (size_t)n * WELEMS + q * 2048
                                  + (size_t)(col0 + r16) * 8;
    short8 B[8][2];
    #pragma unroll
    for (int ks = 0; ks < 8; ++ks)
        #pragma unroll
        for (int nf = 0; nf < 2; ++nf)
            B[ks][nf] = *reinterpret_cast<const short8*>(
                wq + (size_t)ks * 8192 + nf * 128);

    // ---- bias into 2 regs ----
    int c = idx[n];
    f32x4 bv[2];
    #pragma unroll
    for (int nf = 0; nf < 2; ++nf)
        bv[nf] = *reinterpret_cast<const f32x4*>(
            bias + (size_t)c * OUT_SZ + col0 + nf * 16 + q * 4);

    const float* xw = x + (size_t)n * (BATCH * IN_SZ)
                        + (size_t)(rb * 256 + r16) * IN_SZ + q * 8;
    float*       ow = out + (size_t)n * (BATCH * OUT_SZ)
                        + (size_t)(rb * 256 + r16) * OUT_SZ + col0 + q * 4;

    // Two HALF-TILE A buffers: 4 ks x 8 floats = 32 VGPR total.
    f32x4 P0[4][2], P1[4][2];

    // half-step s = 2*t + h  (t = 16-row chunk, h = ks-half)
    auto loadHalf = [&](f32x4 (&P)[4][2], int s) {
        const float* xp = xw + (size_t)(s >> 1) * 16 * IN_SZ + (s & 1) * 128;
        #pragma unroll
        for (int k = 0; k < 4; ++k) {
            P[k][0] = *reinterpret_cast<const f32x4*>(xp + k * 32);
            P[k][1] = *(reinterpret_cast<const f32x4*>(xp + k * 32) + 1);
        }
    };

    loadHalf(P0, 0);
    loadHalf(P1, 1);

    f32x4 acc[2];

    #pragma unroll
    for (int s = 0; s < 32; ++s) {
        if ((s & 1) == 0) {                // new tile: acc init = bias
            acc[0] = bv[0];
            acc[1] = bv[1];
        }

        f32x4 (&Pc)[4][2] = (s & 1) ? P1 : P0;   // static after unroll

        #pragma unroll
        for (int k = 0; k < 4; ++k) {
            int ks = (s & 1) * 4 + k;
            short8 af = cvt8(Pc[k][0], Pc[k][1]);
            #pragma unroll
            for (int nf = 0; nf < 2; ++nf)
                acc[nf] = __builtin_amdgcn_mfma_f32_16x16x32_bf16(
                    B[ks][nf], af, acc[nf], 0, 0, 0);   // swapped: out^T frag
        }

        if (s < 30) loadHalf((s & 1) ? P1 : P0, s + 2);   // refill freed buffer

        if (s & 1) {                       // tile finished: store 16 x 32
            float* op = ow + (size_t)(s >> 1) * 16 * OUT_SZ;
            *reinterpret_cast<f32x4*>(op)      = acc[0];
            *reinterpret_cast<f32x4*>(op + 16) = acc[1];
        }
    }
}

extern "C" void kernel_launch(void* const* d_in, const int* in_sizes, int n_in,
                              void* d_out, int out_size, void* d_ws, size_t ws_size,
                              hipStream_t stream) {
    const float* x    = (const float*)d_in[0];
    const int*   idx  = (const int*)  d_in[1];
    const float* U    = (const float*)d_in[2];
    const float* V    = (const float*)d_in[3];
    const float* bias = (const float*)d_in[4];
    float* out = (float*)d_out;
    unsigned short* wt = (unsigned short*)d_ws;   // 32 MB scratch
    (void)in_sizes; (void)n_in; (void)out_size; (void)ws_size;

    synth_w<<<dim3(512),  dim3(256), 0, stream>>>(U, V, idx, wt);
    gemm_k <<<dim3(2048), dim3(256), 0, stream>>>(x, idx, wt, bias, out);
}

// Round 17
// 303.650 us; speedup vs baseline: 1.0007x; 1.0007x over previous
//
#include <hip/hip_runtime.h>
#include <hip/hip_bf16.h>
#include <stdint.h>

#define IN_SZ   256
#define OUT_SZ  256
#define RANK    60
#define NSEL    256
#define BATCH   1024
#define WELEMS  (IN_SZ * OUT_SZ)   // 65536 elems per channel

typedef __attribute__((ext_vector_type(8))) short          short8;
typedef __attribute__((ext_vector_type(4))) float          f32x4;

static __device__ __forceinline__ unsigned short f32_to_bf16(float f) {
    union { float f; uint32_t u; } c; c.f = f;
    uint32_t u = c.u;
    u += 0x7fffu + ((u >> 16) & 1u);   // RNE
    return (unsigned short)(u >> 16);
}

// pair-packed RNE convert — compiler emits v_cvt_pk_bf16_f32 (same rounding)
static __device__ __forceinline__ short8 cvt8(f32x4 lo, f32x4 hi) {
    union { short8 s; __hip_bfloat162 h[4]; } u;
    u.h[0] = __float22bfloat162_rn(make_float2(lo[0], lo[1]));
    u.h[1] = __float22bfloat162_rn(make_float2(lo[2], lo[3]));
    u.h[2] = __float22bfloat162_rn(make_float2(hi[0], hi[1]));
    u.h[3] = __float22bfloat162_rn(make_float2(hi[2], hi[3]));
    return u.s;
}

// -----------------------------------------------------------------------------
// Kernel 1: W_sel = U[idx] @ V -> bf16 in B-FRAGMENT-MAJOR layout:
//   wt[n][koct*2048 + o*8 + il]   (koct = i>>3, il = i&7)
// (unchanged — verified correct, ~24 µs)
// -----------------------------------------------------------------------------
__global__ __launch_bounds__(256) void synth_w(
    const float* __restrict__ U, const float* __restrict__ V,
    const int* __restrict__ idx, unsigned short* __restrict__ wt)
{
    __shared__ unsigned short Cs[16][2064];

    int bid = blockIdx.x;                  // 512 blocks
    int L   = (bid & 7) * 64 + (bid >> 3); // XCD swizzle: same-ic -> same XCD
    int ic  = L >> 4;
    int g16 = L & 15;

    int tid = threadIdx.x, lane = tid & 63, wv = tid >> 6;

    int arow = lane & 15;
    int c    = idx[g16 * 16 + arow];
    short8 afr[2];
    #pragma unroll
    for (int ks = 0; ks < 2; ++ks) {
        short8 h;
        #pragma unroll
        for (int j = 0; j < 8; ++j) {
            int r = ks * 32 + (lane >> 4) * 8 + j;
            float u = (r < RANK) ? U[c * RANK + r] : 0.f;
            h[j] = (short)f32_to_bf16(u);
        }
        afr[ks] = h;
    }

    const float* Vb = V + (size_t)ic * 2048;
    #pragma unroll 2
    for (int mt = 0; mt < 32; ++mt) {
        int mloc = (wv * 32 + mt) * 16 + (lane & 15);
        f32x4 acc = {};
        #pragma unroll
        for (int ks = 0; ks < 2; ++ks) {
            short8 b;
            #pragma unroll
            for (int j = 0; j < 8; ++j) {
                int r = ks * 32 + (lane >> 4) * 8 + j;
                float v = (r < RANK) ? Vb[(size_t)r * WELEMS + mloc] : 0.f;
                b[j] = (short)f32_to_bf16(v);
            }
            acc = __builtin_amdgcn_mfma_f32_16x16x32_bf16(afr[ks], b, acc, 0, 0, 0);
        }
        #pragma unroll
        for (int j = 0; j < 4; ++j) {
            int nl = (lane >> 4) * 4 + j;
            Cs[nl][wv * 512 + mt * 16 + (lane & 15)] = f32_to_bf16(acc[j]);
        }
    }
    __syncthreads();

    #pragma unroll
    for (int t0 = 0; t0 < 16; ++t0) {
        int t  = t0 * 256 + tid;
        int nl = t >> 8;
        int o  = t & 255;
        short8 h;
        #pragma unroll
        for (int il = 0; il < 8; ++il) h[il] = (short)Cs[nl][il * 256 + o];
        int n = g16 * 16 + nl;
        size_t base = (size_t)n * WELEMS + (size_t)ic * 2048 + (size_t)o * 8;
        *reinterpret_cast<short8*>(wt + base) = h;
    }
}

// -----------------------------------------------------------------------------
// Kernel 2: B-IN-REGISTERS GEMM. Zero LDS, zero barriers. 2048 blocks of 256
// threads; block = (n, col-half cb, row-quarter rb); wave owns 32 cols x 256
// rows. Its W column-slice (8 ks x 2 nf x short8 = 64 VGPR) is loaded from
// global ONCE (L2-hot, same-n blocks XCD-pinned); bias in 2 regs; acc init =
// bias. Steady state: only the A-stream touches memory — per-lane coalesced
// global x loads, half-tile double buffer (R15's proven scheme). No per-MFMA
// LDS reads (R15 paid 8.4 MB/CU = ~41 us of LDS pipe), no vmcnt/lgkm coupling.
// __launch_bounds__(256,3): cap ~170 regs, demand ~130 -> no spill; 3 blk/CU.
// -----------------------------------------------------------------------------
__global__ __launch_bounds__(256, 3) void gemm_k(
    const float* __restrict__ x, const int* __restrict__ idx,
    const unsigned short* __restrict__ wt, const float* __restrict__ bias,
    float* __restrict__ out)
{
    int bid = blockIdx.x;                  // 2048 blocks
    int L   = (bid & 7) * 256 + (bid >> 3);
    int n   = L >> 3;                      // 8 blocks of same n -> same XCD
    int sub = L & 7;
    int cb  = sub & 1;                     // col half   (128 cols)
    int rb  = sub >> 1;                    // row quarter (256 rows)

    int tid  = threadIdx.x;
    int lane = tid & 63;
    int wv   = tid >> 6;                   // 0..3
    int r16  = lane & 15;
    int q    = lane >> 4;

    int col0 = cb * 128 + wv * 32;         // wave's 32-col base

    // ---- B into registers: 16 x dwordx4, once ----
    const unsigned short* wq = wt + (size_t)n * WELEMS + q * 2048
                                  + (size_t)(col0 + r16) * 8;
    short8 B[8][2];
    #pragma unroll
    for (int ks = 0; ks < 8; ++ks)
        #pragma unroll
        for (int nf = 0; nf < 2; ++nf)
            B[ks][nf] = *reinterpret_cast<const short8*>(
                wq + (size_t)ks * 8192 + nf * 128);

    // ---- bias into 2 regs ----
    int c = idx[n];
    f32x4 bv[2];
    #pragma unroll
    for (int nf = 0; nf < 2; ++nf)
        bv[nf] = *reinterpret_cast<const f32x4*>(
            bias + (size_t)c * OUT_SZ + col0 + nf * 16 + q * 4);

    const float* xw = x + (size_t)n * (BATCH * IN_SZ)
                        + (size_t)(rb * 256 + r16) * IN_SZ + q * 8;
    float*       ow = out + (size_t)n * (BATCH * OUT_SZ)
                        + (size_t)(rb * 256 + r16) * OUT_SZ + col0 + q * 4;

    // Two HALF-TILE A buffers: 4 ks x 8 floats = 32 VGPR total.
    f32x4 P0[4][2], P1[4][2];

    // half-step s = 2*t + h  (t = 16-row chunk, h = ks-half)
    auto loadHalf = [&](f32x4 (&P)[4][2], int s) {
        const float* xp = xw + (size_t)(s >> 1) * 16 * IN_SZ + (s & 1) * 128;
        #pragma unroll
        for (int k = 0; k < 4; ++k) {
            P[k][0] = *reinterpret_cast<const f32x4*>(xp + k * 32);
            P[k][1] = *(reinterpret_cast<const f32x4*>(xp + k * 32) + 1);
        }
    };

    loadHalf(P0, 0);
    loadHalf(P1, 1);

    f32x4 acc[2];

    #pragma unroll
    for (int s = 0; s < 32; ++s) {
        if ((s & 1) == 0) {                // new tile: acc init = bias
            acc[0] = bv[0];
            acc[1] = bv[1];
        }

        f32x4 (&Pc)[4][2] = (s & 1) ? P1 : P0;   // static after unroll

        #pragma unroll
        for (int k = 0; k < 4; ++k) {
            int ks = (s & 1) * 4 + k;
            short8 af = cvt8(Pc[k][0], Pc[k][1]);
            #pragma unroll
            for (int nf = 0; nf < 2; ++nf)
                acc[nf] = __builtin_amdgcn_mfma_f32_16x16x32_bf16(
                    B[ks][nf], af, acc[nf], 0, 0, 0);   // swapped: out^T frag
        }

        if (s < 30) loadHalf((s & 1) ? P1 : P0, s + 2);   // refill freed buffer

        if (s & 1) {                       // tile finished: store 16 x 32
            float* op = ow + (size_t)(s >> 1) * 16 * OUT_SZ;
            *reinterpret_cast<f32x4*>(op)      = acc[0];
            *reinterpret_cast<f32x4*>(op + 16) = acc[1];
        }
    }
}

extern "C" void kernel_launch(void* const* d_in, const int* in_sizes, int n_in,
                              void* d_out, int out_size, void* d_ws, size_t ws_size,
                              hipStream_t stream) {
    const float* x    = (const float*)d_in[0];
    const int*   idx  = (const int*)  d_in[1];
    const float* U    = (const float*)d_in[2];
    const float* V    = (const float*)d_in[3];
    const float* bias = (const float*)d_in[4];
    float* out = (float*)d_out;
    unsigned short* wt = (unsigned short*)d_ws;   // 32 MB scratch
    (void)in_sizes; (void)n_in; (void)out_size; (void)ws_size;

    synth_w<<<dim3(512),  dim3(256), 0, stream>>>(U, V, idx, wt);
    gemm_k <<<dim3(2048), dim3(256), 0, stream>>>(x, idx, wt, bias, out);
}

// Round 18
// 303.456 us; speedup vs baseline: 1.0014x; 1.0006x over previous
//
#include <hip/hip_runtime.h>
#include <hip/hip_bf16.h>
#include <stdint.h>

#define IN_SZ   256
#define OUT_SZ  256
#define RANK    60
#define NSEL    256
#define BATCH   1024
#define WELEMS  (IN_SZ * OUT_SZ)   // 65536 elems per channel

typedef __attribute__((ext_vector_type(8))) short          short8;
typedef __attribute__((ext_vector_type(4))) float          f32x4;

static __device__ __forceinline__ unsigned short f32_to_bf16(float f) {
    union { float f; uint32_t u; } c; c.f = f;
    uint32_t u = c.u;
    u += 0x7fffu + ((u >> 16) & 1u);   // RNE
    return (unsigned short)(u >> 16);
}

// pair-packed RNE convert — compiler emits v_cvt_pk_bf16_f32 (same rounding)
static __device__ __forceinline__ short8 cvt8(f32x4 lo, f32x4 hi) {
    union { short8 s; __hip_bfloat162 h[4]; } u;
    u.h[0] = __float22bfloat162_rn(make_float2(lo[0], lo[1]));
    u.h[1] = __float22bfloat162_rn(make_float2(lo[2], lo[3]));
    u.h[2] = __float22bfloat162_rn(make_float2(hi[0], hi[1]));
    u.h[3] = __float22bfloat162_rn(make_float2(hi[2], hi[3]));
    return u.s;
}

// -----------------------------------------------------------------------------
// Kernel 1: W_sel = U[idx] @ V -> bf16 in B-FRAGMENT-MAJOR layout:
//   wt[n][koct*2048 + o*8 + il]   (koct = i>>3, il = i&7)
// (unchanged — verified correct, ~24 µs)
// -----------------------------------------------------------------------------
__global__ __launch_bounds__(256) void synth_w(
    const float* __restrict__ U, const float* __restrict__ V,
    const int* __restrict__ idx, unsigned short* __restrict__ wt)
{
    __shared__ unsigned short Cs[16][2064];

    int bid = blockIdx.x;                  // 512 blocks
    int L   = (bid & 7) * 64 + (bid >> 3); // XCD swizzle: same-ic -> same XCD
    int ic  = L >> 4;
    int g16 = L & 15;

    int tid = threadIdx.x, lane = tid & 63, wv = tid >> 6;

    int arow = lane & 15;
    int c    = idx[g16 * 16 + arow];
    short8 afr[2];
    #pragma unroll
    for (int ks = 0; ks < 2; ++ks) {
        short8 h;
        #pragma unroll
        for (int j = 0; j < 8; ++j) {
            int r = ks * 32 + (lane >> 4) * 8 + j;
            float u = (r < RANK) ? U[c * RANK + r] : 0.f;
            h[j] = (short)f32_to_bf16(u);
        }
        afr[ks] = h;
    }

    const float* Vb = V + (size_t)ic * 2048;
    #pragma unroll 2
    for (int mt = 0; mt < 32; ++mt) {
        int mloc = (wv * 32 + mt) * 16 + (lane & 15);
        f32x4 acc = {};
        #pragma unroll
        for (int ks = 0; ks < 2; ++ks) {
            short8 b;
            #pragma unroll
            for (int j = 0; j < 8; ++j) {
                int r = ks * 32 + (lane >> 4) * 8 + j;
                float v = (r < RANK) ? Vb[(size_t)r * WELEMS + mloc] : 0.f;
                b[j] = (short)f32_to_bf16(v);
            }
            acc = __builtin_amdgcn_mfma_f32_16x16x32_bf16(afr[ks], b, acc, 0, 0, 0);
        }
        #pragma unroll
        for (int j = 0; j < 4; ++j) {
            int nl = (lane >> 4) * 4 + j;
            Cs[nl][wv * 512 + mt * 16 + (lane & 15)] = f32_to_bf16(acc[j]);
        }
    }
    __syncthreads();

    #pragma unroll
    for (int t0 = 0; t0 < 16; ++t0) {
        int t  = t0 * 256 + tid;
        int nl = t >> 8;
        int o  = t & 255;
        short8 h;
        #pragma unroll
        for (int il = 0; il < 8; ++il) h[il] = (short)Cs[nl][il * 256 + o];
        int n = g16 * 16 + nl;
        size_t base = (size_t)n * WELEMS + (size_t)ic * 2048 + (size_t)o * 8;
        *reinterpret_cast<short8*>(wt + base) = h;
    }
}

// -----------------------------------------------------------------------------
// Kernel 2: B-IN-REGISTERS GEMM. Zero LDS, zero barriers. 2048 blocks of 256
// threads; block = (n, col-half cb, row-quarter rb); wave owns 32 cols x 256
// rows. Its W column-slice (8 ks x 2 nf x short8 = 64 VGPR) is loaded from
// global ONCE (L2-hot, same-n blocks XCD-pinned); bias in 2 regs; acc init =
// bias. Steady state: only the A-stream touches memory — per-lane coalesced
// global x loads, half-tile double buffer (R15's proven scheme). No per-MFMA
// LDS reads (R15 paid 8.4 MB/CU = ~41 us of LDS pipe), no vmcnt/lgkm coupling.
// __launch_bounds__(256,3): cap ~170 regs, demand ~130 -> no spill; 3 blk/CU.
// -----------------------------------------------------------------------------
__global__ __launch_bounds__(256, 3) void gemm_k(
    const float* __restrict__ x, const int* __restrict__ idx,
    const unsigned short* __restrict__ wt, const float* __restrict__ bias,
    float* __restrict__ out)
{
    int bid = blockIdx.x;                  // 2048 blocks
    int L   = (bid & 7) * 256 + (bid >> 3);
    int n   = L >> 3;                      // 8 blocks of same n -> same XCD
    int sub = L & 7;
    int cb  = sub & 1;                     // col half   (128 cols)
    int rb  = sub >> 1;                    // row quarter (256 rows)

    int tid  = threadIdx.x;
    int lane = tid & 63;
    int wv   = tid >> 6;                   // 0..3
    int r16  = lane & 15;
    int q    = lane >> 4;

    int col0 = cb * 128 + wv * 32;         // wave's 32-col base

    // ---- B into registers: 16 x dwordx4, once ----
    const unsigned short* wq = wt + (size_t)n * WELEMS + q * 2048
                                  + (size_t)(col0 + r16) * 8;
    short8 B[8][2];
    #pragma unroll
    for (int ks = 0; ks < 8; ++ks)
        #pragma unroll
        for (int nf = 0; nf < 2; ++nf)
            B[ks][nf] = *reinterpret_cast<const short8*>(
                wq + (size_t)ks * 8192 + nf * 128);

    // ---- bias into 2 regs ----
    int c = idx[n];
    f32x4 bv[2];
    #pragma unroll
    for (int nf = 0; nf < 2; ++nf)
        bv[nf] = *reinterpret_cast<const f32x4*>(
            bias + (size_t)c * OUT_SZ + col0 + nf * 16 + q * 4);

    const float* xw = x + (size_t)n * (BATCH * IN_SZ)
                        + (size_t)(rb * 256 + r16) * IN_SZ + q * 8;
    float*       ow = out + (size_t)n * (BATCH * OUT_SZ)
                        + (size_t)(rb * 256 + r16) * OUT_SZ + col0 + q * 4;

    // Two HALF-TILE A buffers: 4 ks x 8 floats = 32 VGPR total.
    f32x4 P0[4][2], P1[4][2];

    // half-step s = 2*t + h  (t = 16-row chunk, h = ks-half)
    auto loadHalf = [&](f32x4 (&P)[4][2], int s) {
        const float* xp = xw + (size_t)(s >> 1) * 16 * IN_SZ + (s & 1) * 128;
        #pragma unroll
        for (int k = 0; k < 4; ++k) {
            P[k][0] = *reinterpret_cast<const f32x4*>(xp + k * 32);
            P[k][1] = *(reinterpret_cast<const f32x4*>(xp + k * 32) + 1);
        }
    };

    loadHalf(P0, 0);
    loadHalf(P1, 1);

    f32x4 acc[2];

    #pragma unroll
    for (int s = 0; s < 32; ++s) {
        if ((s & 1) == 0) {                // new tile: acc init = bias
            acc[0] = bv[0];
            acc[1] = bv[1];
        }

        f32x4 (&Pc)[4][2] = (s & 1) ? P1 : P0;   // static after unroll

        #pragma unroll
        for (int k = 0; k < 4; ++k) {
            int ks = (s & 1) * 4 + k;
            short8 af = cvt8(Pc[k][0], Pc[k][1]);
            #pragma unroll
            for (int nf = 0; nf < 2; ++nf)
                acc[nf] = __builtin_amdgcn_mfma_f32_16x16x32_bf16(
                    B[ks][nf], af, acc[nf], 0, 0, 0);   // swapped: out^T frag
        }

        if (s < 30) loadHalf((s & 1) ? P1 : P0, s + 2);   // refill freed buffer

        if (s & 1) {                       // tile finished: store 16 x 32
            float* op = ow + (size_t)(s >> 1) * 16 * OUT_SZ;
            *reinterpret_cast<f32x4*>(op)      = acc[0];
            *reinterpret_cast<f32x4*>(op + 16) = acc[1];
        }
    }
}

extern "C" void kernel_launch(void* const* d_in, const int* in_sizes, int n_in,
                              void* d_out, int out_size, void* d_ws, size_t ws_size,
                              hipStream_t stream) {
    const float* x    = (const float*)d_in[0];
    const int*   idx  = (const int*)  d_in[1];
    const float* U    = (const float*)d_in[2];
    const float* V    = (const float*)d_in[3];
    const float* bias = (const float*)d_in[4];
    float* out = (float*)d_out;
    unsigned short* wt = (unsigned short*)d_ws;   // 32 MB scratch
    (void)in_sizes; (void)n_in; (void)out_size; (void)ws_size;

    synth_w<<<dim3(512),  dim3(256), 0, stream>>>(U, V, idx, wt);
    gemm_k <<<dim3(2048), dim3(256), 0, stream>>>(x, idx, wt, bias, out);
}

// Round 19
// 256.479 us; speedup vs baseline: 1.1848x; 1.1832x over previous
//
#include <hip/hip_runtime.h>
#include <hip/hip_bf16.h>
#include <stdint.h>

#define IN_SZ   256
#define OUT_SZ  256
#define RANK    60
#define NSEL    256
#define BATCH   1024
#define WELEMS  (IN_SZ * OUT_SZ)   // 65536 elems per channel

typedef __attribute__((ext_vector_type(8))) short          short8;
typedef __attribute__((ext_vector_type(4))) float          f32x4;

static __device__ __forceinline__ unsigned short f32_to_bf16(float f) {
    union { float f; uint32_t u; } c; c.f = f;
    uint32_t u = c.u;
    u += 0x7fffu + ((u >> 16) & 1u);   // RNE
    return (unsigned short)(u >> 16);
}

// pair-packed RNE convert — compiler emits v_cvt_pk_bf16_f32 (same rounding)
static __device__ __forceinline__ short8 cvt8(f32x4 lo, f32x4 hi) {
    union { short8 s; __hip_bfloat162 h[4]; } u;
    u.h[0] = __float22bfloat162_rn(make_float2(lo[0], lo[1]));
    u.h[1] = __float22bfloat162_rn(make_float2(lo[2], lo[3]));
    u.h[2] = __float22bfloat162_rn(make_float2(hi[0], hi[1]));
    u.h[3] = __float22bfloat162_rn(make_float2(hi[2], hi[3]));
    return u.s;
}

// -----------------------------------------------------------------------------
// Kernel 1: W_sel = U[idx] @ V -> bf16 in B-FRAGMENT-MAJOR layout:
//   wt[n][koct*2048 + o*8 + il]   (koct = i>>3, il = i&7)
// (unchanged — verified correct, ~24 µs)
// -----------------------------------------------------------------------------
__global__ __launch_bounds__(256) void synth_w(
    const float* __restrict__ U, const float* __restrict__ V,
    const int* __restrict__ idx, unsigned short* __restrict__ wt)
{
    __shared__ unsigned short Cs[16][2064];

    int bid = blockIdx.x;                  // 512 blocks
    int L   = (bid & 7) * 64 + (bid >> 3); // XCD swizzle: same-ic -> same XCD
    int ic  = L >> 4;
    int g16 = L & 15;

    int tid = threadIdx.x, lane = tid & 63, wv = tid >> 6;

    int arow = lane & 15;
    int c    = idx[g16 * 16 + arow];
    short8 afr[2];
    #pragma unroll
    for (int ks = 0; ks < 2; ++ks) {
        short8 h;
        #pragma unroll
        for (int j = 0; j < 8; ++j) {
            int r = ks * 32 + (lane >> 4) * 8 + j;
            float u = (r < RANK) ? U[c * RANK + r] : 0.f;
            h[j] = (short)f32_to_bf16(u);
        }
        afr[ks] = h;
    }

    const float* Vb = V + (size_t)ic * 2048;
    #pragma unroll 2
    for (int mt = 0; mt < 32; ++mt) {
        int mloc = (wv * 32 + mt) * 16 + (lane & 15);
        f32x4 acc = {};
        #pragma unroll
        for (int ks = 0; ks < 2; ++ks) {
            short8 b;
            #pragma unroll
            for (int j = 0; j < 8; ++j) {
                int r = ks * 32 + (lane >> 4) * 8 + j;
                float v = (r < RANK) ? Vb[(size_t)r * WELEMS + mloc] : 0.f;
                b[j] = (short)f32_to_bf16(v);
            }
            acc = __builtin_amdgcn_mfma_f32_16x16x32_bf16(afr[ks], b, acc, 0, 0, 0);
        }
        #pragma unroll
        for (int j = 0; j < 4; ++j) {
            int nl = (lane >> 4) * 4 + j;
            Cs[nl][wv * 512 + mt * 16 + (lane & 15)] = f32_to_bf16(acc[j]);
        }
    }
    __syncthreads();

    #pragma unroll
    for (int t0 = 0; t0 < 16; ++t0) {
        int t  = t0 * 256 + tid;
        int nl = t >> 8;
        int o  = t & 255;
        short8 h;
        #pragma unroll
        for (int il = 0; il < 8; ++il) h[il] = (short)Cs[nl][il * 256 + o];
        int n = g16 * 16 + nl;
        size_t base = (size_t)n * WELEMS + (size_t)ic * 2048 + (size_t)o * 8;
        *reinterpret_cast<short8*>(wt + base) = h;
    }
}

// -----------------------------------------------------------------------------
// Kernel 2: W-RESIDENT-IN-LDS GEMM, 16-wave TLP. One block per n (256 blocks,
// 1024 threads = 16 waves = 4/SIMD). W[n] (128 KB) DMA'd to LDS once + bias;
// ONE barrier; then free-running waves, each owning 64 rows (4 tiles of 16).
// A per-lane from global (coalesced, half-tile double buffer = 32 VGPR),
// B from LDS (conflict-free), acc init = bias.
// vs R15 (8 waves/CU): 4 waves/SIMD cover each other's ~1500-cyc A-refill
// stalls -> HBM queue stays full by TLP, not prefetch depth (which is
// register-capped: 128 arch + 64 acc at this block size — R13/R14/R18 lesson).
// -----------------------------------------------------------------------------
__global__ __launch_bounds__(1024, 1) void gemm_k(
    const float* __restrict__ x, const int* __restrict__ idx,
    const unsigned short* __restrict__ wt, const float* __restrict__ bias,
    float* __restrict__ out)
{
    __shared__ __align__(16) unsigned short Wl[WELEMS];   // 128 KB
    __shared__ __align__(16) float          Bl[256];      // 1 KB bias

    int n    = blockIdx.x;                 // 0..255, one n per block
    int tid  = threadIdx.x;
    int lane = tid & 63;
    int wv   = tid >> 6;                   // 0..15
    int r16  = lane & 15;
    int q    = lane >> 4;

    const unsigned short* wn = wt + (size_t)n * WELEMS;

    // ---- stage W[n]: 128 x 1KB linear DMA segments (8 per wave) ----
    #pragma unroll
    for (int j = 0; j < 8; ++j) {
        int g = wv * 8 + j;                // 0..127
        __builtin_amdgcn_global_load_lds(
            (const __attribute__((address_space(1))) void*)(wn + g * 512 + lane * 8),
            (__attribute__((address_space(3))) void*)(&Wl[g * 512]),
            16, 0, 0);
    }
    // ---- stage bias[c] ----
    int c = idx[n];
    if (tid < 64) {
        f32x4 b = *reinterpret_cast<const f32x4*>(bias + (size_t)c * OUT_SZ + tid * 4);
        *reinterpret_cast<f32x4*>(&Bl[tid * 4]) = b;
    }
    __syncthreads();   // the only barrier (drains DMA + ds_write)

    const float* xw = x + (size_t)n * (BATCH * IN_SZ)
                        + (size_t)(wv * 64 + r16) * IN_SZ + q * 8;
    float*       ow = out + (size_t)n * (BATCH * OUT_SZ)
                        + (size_t)(wv * 64 + r16) * OUT_SZ + q * 4;
    const char*  wl = reinterpret_cast<const char*>(Wl);
    int lq = q * 4096 + r16 * 16;          // lane's byte base into Wl

    // Two HALF-TILE prefetch buffers: 4 ks x 8 floats = 32 VGPR total.
    f32x4 P0[4][2], P1[4][2];

    // half-step s = 2*t + h  (t = 16-row chunk 0..3, h = ks-half)
    auto loadHalf = [&](f32x4 (&P)[4][2], int s) {
        const float* xp = xw + (size_t)(s >> 1) * 16 * IN_SZ + (s & 1) * 128;
        #pragma unroll
        for (int k = 0; k < 4; ++k) {
            P[k][0] = *reinterpret_cast<const f32x4*>(xp + k * 32);
            P[k][1] = *(reinterpret_cast<const f32x4*>(xp + k * 32) + 1);
        }
    };

    loadHalf(P0, 0);
    loadHalf(P1, 1);

    f32x4 acc[16];

    #pragma unroll
    for (int s = 0; s < 8; ++s) {
        if ((s & 1) == 0) {                // new tile: acc init = bias
            #pragma unroll
            for (int nf = 0; nf < 16; ++nf)
                acc[nf] = *reinterpret_cast<const f32x4*>(&Bl[nf * 16 + q * 4]);
        }

        f32x4 (&Pc)[4][2] = (s & 1) ? P1 : P0;   // static after unroll

        #pragma unroll
        for (int k = 0; k < 4; ++k) {
            int ks = (s & 1) * 4 + k;
            short8 af = cvt8(Pc[k][0], Pc[k][1]);
            #pragma unroll
            for (int nf = 0; nf < 16; ++nf) {
                short8 bf = *reinterpret_cast<const short8*>(
                    wl + lq + ks * 16384 + nf * 256);
                acc[nf] = __builtin_amdgcn_mfma_f32_16x16x32_bf16(
                    bf, af, acc[nf], 0, 0, 0);   // swapped: out^T frag
            }
        }

        if (s < 6) loadHalf((s & 1) ? P1 : P0, s + 2);   // refill freed buffer

        if (s & 1) {                       // tile finished: store 16 x 256
            float* op = ow + (size_t)(s >> 1) * 16 * OUT_SZ;
            #pragma unroll
            for (int nf = 0; nf < 16; ++nf)
                *reinterpret_cast<f32x4*>(op + nf * 16) = acc[nf];
        }
    }
}

extern "C" void kernel_launch(void* const* d_in, const int* in_sizes, int n_in,
                              void* d_out, int out_size, void* d_ws, size_t ws_size,
                              hipStream_t stream) {
    const float* x    = (const float*)d_in[0];
    const int*   idx  = (const int*)  d_in[1];
    const float* U    = (const float*)d_in[2];
    const float* V    = (const float*)d_in[3];
    const float* bias = (const float*)d_in[4];
    float* out = (float*)d_out;
    unsigned short* wt = (unsigned short*)d_ws;   // 32 MB scratch
    (void)in_sizes; (void)n_in; (void)out_size; (void)ws_size;

    synth_w<<<dim3(512), dim3(256), 0, stream>>>(U, V, idx, wt);
    gemm_k <<<dim3(256), dim3(1024), 0, stream>>>(x, idx, wt, bias, out);
}